// Round 1
// baseline (481.077 us; speedup 1.0000x reference)
//
#include <hip/hip_runtime.h>

#define RES 300
#define NC 48
#define RES2 (RES * RES)

__device__ __forceinline__ int clampi(int v, int lo, int hi) {
    return v < lo ? lo : (v > hi ? hi : v);
}

// (3, NC, RES, RES) -> (3, RES, RES, NC)   channel-last
__global__ __launch_bounds__(256) void tp_planes_kernel(const float* __restrict__ in,
                                                        float* __restrict__ out) {
    unsigned idx = blockIdx.x * 256u + threadIdx.x;
    if (idx >= 3u * RES2) return;
    unsigned p  = idx / RES2;
    unsigned yx = idx - p * RES2;
    const float* src = in + (size_t)p * NC * RES2 + yx;
    float v[NC];
#pragma unroll
    for (int c = 0; c < NC; ++c) v[c] = src[(size_t)c * RES2];
    float4* dst = reinterpret_cast<float4*>(out + (size_t)idx * NC);
#pragma unroll
    for (int i = 0; i < NC / 4; ++i)
        dst[i] = make_float4(v[4 * i], v[4 * i + 1], v[4 * i + 2], v[4 * i + 3]);
}

// (3, NC, RES, 1) -> (3, RES, NC)   channel-last
__global__ __launch_bounds__(256) void tp_lines_kernel(const float* __restrict__ in,
                                                       float* __restrict__ out) {
    unsigned idx = blockIdx.x * 256u + threadIdx.x;
    if (idx >= 3u * RES) return;
    unsigned p = idx / RES;
    unsigned y = idx - p * RES;
#pragma unroll
    for (int c = 0; c < NC; ++c)
        out[(size_t)idx * NC + c] = in[((size_t)p * NC + c) * RES + y];
}

// one thread per (point, float4 channel group): q in [0,36), p = q/12, c4 = q%12
__global__ __launch_bounds__(256) void encode_kernel(const float* __restrict__ x,
                                                     const float* __restrict__ pt,  // (3,RES,RES,NC)
                                                     const float* __restrict__ lt,  // (3,RES,NC)
                                                     float* __restrict__ out,
                                                     unsigned N) {
    unsigned gid = blockIdx.x * 256u + threadIdx.x;
    if (gid >= N * 36u) return;
    unsigned n  = gid / 36u;
    unsigned q  = gid - n * 36u;
    unsigned p  = q / 12u;
    unsigned c4 = q - p * 12u;

    float xv0 = x[3u * n + 0u];
    float xv1 = x[3u * n + 1u];
    float xv2 = x[3u * n + 2u];

    // plane p coordinate selection:
    // p=0: gx=xs0 gy=xs1 gl=xs2 ; p=1: gx=xs0 gy=xs2 gl=xs1 ; p=2: gx=xs1 gy=xs2 gl=xs0
    float gxv = (p == 2u) ? xv1 : xv0;
    float gyv = (p == 0u) ? xv1 : xv2;
    float glv = (p == 0u) ? xv2 : ((p == 1u) ? xv1 : xv0);

    // mirror reference fp32 arithmetic
    float gxs = 2.0f * gxv - 1.0f;
    float gys = 2.0f * gyv - 1.0f;
    float gls = 2.0f * glv - 1.0f;
    float px = (gxs + 1.0f) * 0.5f * (float)(RES - 1);
    float py = (gys + 1.0f) * 0.5f * (float)(RES - 1);
    float pl = (gls + 1.0f) * 0.5f * (float)(RES - 1);

    float x0f = floorf(px), y0f = floorf(py), l0f = floorf(pl);
    float wx = px - x0f, wy = py - y0f, wl = pl - l0f;

    int ix0 = clampi((int)x0f, 0, RES - 1);
    int ix1 = ix0 + 1 > RES - 1 ? RES - 1 : ix0 + 1;
    int iy0 = clampi((int)y0f, 0, RES - 1);
    int iy1 = iy0 + 1 > RES - 1 ? RES - 1 : iy0 + 1;
    int il0 = clampi((int)l0f, 0, RES - 1);
    int il1 = il0 + 1 > RES - 1 ? RES - 1 : il0 + 1;

    unsigned cbase = c4 * 4u;
    const float* pb = pt + (size_t)p * RES2 * NC;
    unsigned o00 = ((unsigned)iy0 * RES + (unsigned)ix0) * NC + cbase;
    unsigned o01 = ((unsigned)iy0 * RES + (unsigned)ix1) * NC + cbase;
    unsigned o10 = ((unsigned)iy1 * RES + (unsigned)ix0) * NC + cbase;
    unsigned o11 = ((unsigned)iy1 * RES + (unsigned)ix1) * NC + cbase;

    float4 f00 = *reinterpret_cast<const float4*>(pb + o00);
    float4 f01 = *reinterpret_cast<const float4*>(pb + o01);
    float4 f10 = *reinterpret_cast<const float4*>(pb + o10);
    float4 f11 = *reinterpret_cast<const float4*>(pb + o11);

    float w00 = (1.0f - wx) * (1.0f - wy);
    float w01 = wx * (1.0f - wy);
    float w10 = (1.0f - wx) * wy;
    float w11 = wx * wy;

    float4 plane_v;
    plane_v.x = f00.x * w00 + f01.x * w01 + f10.x * w10 + f11.x * w11;
    plane_v.y = f00.y * w00 + f01.y * w01 + f10.y * w10 + f11.y * w11;
    plane_v.z = f00.z * w00 + f01.z * w01 + f10.z * w10 + f11.z * w11;
    plane_v.w = f00.w * w00 + f01.w * w01 + f10.w * w10 + f11.w * w11;

    const float* lb = lt + (size_t)p * RES * NC + cbase;
    float4 l0 = *reinterpret_cast<const float4*>(lb + (size_t)il0 * NC);
    float4 l1 = *reinterpret_cast<const float4*>(lb + (size_t)il1 * NC);

    float wl0 = 1.0f - wl;
    float4 line_v;
    line_v.x = l0.x * wl0 + l1.x * wl;
    line_v.y = l0.y * wl0 + l1.y * wl;
    line_v.z = l0.z * wl0 + l1.z * wl;
    line_v.w = l0.w * wl0 + l1.w * wl;

    float4 r;
    r.x = plane_v.x * line_v.x;
    r.y = plane_v.y * line_v.y;
    r.z = plane_v.z * line_v.z;
    r.w = plane_v.w * line_v.w;

    *reinterpret_cast<float4*>(out + (size_t)n * 144u + (size_t)q * 4u) = r;
}

// correctness fallback if d_ws too small: gather from the original channel-major layout
__global__ __launch_bounds__(256) void encode_fallback_kernel(const float* __restrict__ x,
                                                              const float* __restrict__ plane,  // (3,NC,RES,RES)
                                                              const float* __restrict__ line,   // (3,NC,RES,1)
                                                              float* __restrict__ out,
                                                              unsigned N) {
    unsigned gid = blockIdx.x * 256u + threadIdx.x;
    if (gid >= N * 36u) return;
    unsigned n  = gid / 36u;
    unsigned q  = gid - n * 36u;
    unsigned p  = q / 12u;
    unsigned c4 = q - p * 12u;

    float xv0 = x[3u * n + 0u];
    float xv1 = x[3u * n + 1u];
    float xv2 = x[3u * n + 2u];
    float gxv = (p == 2u) ? xv1 : xv0;
    float gyv = (p == 0u) ? xv1 : xv2;
    float glv = (p == 0u) ? xv2 : ((p == 1u) ? xv1 : xv0);

    float gxs = 2.0f * gxv - 1.0f;
    float gys = 2.0f * gyv - 1.0f;
    float gls = 2.0f * glv - 1.0f;
    float px = (gxs + 1.0f) * 0.5f * (float)(RES - 1);
    float py = (gys + 1.0f) * 0.5f * (float)(RES - 1);
    float pl = (gls + 1.0f) * 0.5f * (float)(RES - 1);

    float x0f = floorf(px), y0f = floorf(py), l0f = floorf(pl);
    float wx = px - x0f, wy = py - y0f, wl = pl - l0f;

    int ix0 = clampi((int)x0f, 0, RES - 1);
    int ix1 = ix0 + 1 > RES - 1 ? RES - 1 : ix0 + 1;
    int iy0 = clampi((int)y0f, 0, RES - 1);
    int iy1 = iy0 + 1 > RES - 1 ? RES - 1 : iy0 + 1;
    int il0 = clampi((int)l0f, 0, RES - 1);
    int il1 = il0 + 1 > RES - 1 ? RES - 1 : il0 + 1;

    float w00 = (1.0f - wx) * (1.0f - wy);
    float w01 = wx * (1.0f - wy);
    float w10 = (1.0f - wx) * wy;
    float w11 = wx * wy;
    float wl0 = 1.0f - wl;

    float4 r;
    float* rp = &r.x;
#pragma unroll
    for (int cc = 0; cc < 4; ++cc) {
        unsigned c = c4 * 4u + (unsigned)cc;
        const float* pp = plane + ((size_t)p * NC + c) * RES2;
        float f00 = pp[(size_t)iy0 * RES + ix0];
        float f01 = pp[(size_t)iy0 * RES + ix1];
        float f10 = pp[(size_t)iy1 * RES + ix0];
        float f11 = pp[(size_t)iy1 * RES + ix1];
        float pv = f00 * w00 + f01 * w01 + f10 * w10 + f11 * w11;
        const float* lp = line + ((size_t)p * NC + c) * RES;
        float lv = lp[il0] * wl0 + lp[il1] * wl;
        rp[cc] = pv * lv;
    }
    *reinterpret_cast<float4*>(out + (size_t)n * 144u + (size_t)q * 4u) = r;
}

extern "C" void kernel_launch(void* const* d_in, const int* in_sizes, int n_in,
                              void* d_out, int out_size, void* d_ws, size_t ws_size,
                              hipStream_t stream) {
    const float* x     = (const float*)d_in[0];
    const float* plane = (const float*)d_in[1];
    const float* line  = (const float*)d_in[2];
    float* out = (float*)d_out;
    unsigned N = (unsigned)(in_sizes[0] / 3);

    size_t plane_t_elems = (size_t)3 * RES2 * NC;
    size_t line_t_elems  = (size_t)3 * RES * NC;
    size_t need = (plane_t_elems + line_t_elems) * sizeof(float);

    unsigned total  = N * 36u;
    unsigned blocks = (total + 255u) / 256u;

    if (ws_size >= need) {
        float* plane_t = (float*)d_ws;
        float* line_t  = plane_t + plane_t_elems;
        tp_planes_kernel<<<(3u * RES2 + 255u) / 256u, 256, 0, stream>>>(plane, plane_t);
        tp_lines_kernel<<<(3u * RES + 255u) / 256u, 256, 0, stream>>>(line, line_t);
        encode_kernel<<<blocks, 256, 0, stream>>>(x, plane_t, line_t, out, N);
    } else {
        encode_fallback_kernel<<<blocks, 256, 0, stream>>>(x, plane, line, out, N);
    }
}

// Round 2
// 313.904 us; speedup vs baseline: 1.5326x; 1.5326x over previous
//
#include <hip/hip_runtime.h>
#include <hip/hip_fp16.h>

#define RES 300
#define NC 48
#define RES2 (RES * RES)

typedef float f32x4 __attribute__((ext_vector_type(4)));
typedef unsigned int u32x4 __attribute__((ext_vector_type(4)));

struct alignas(8) h4 { __half2 a, b; };

__device__ __forceinline__ int clampi(int v, int lo, int hi) {
    return v < lo ? lo : (v > hi ? hi : v);
}

// (3, NC, RES, RES) fp32 -> (3, RES, RES, NC) fp16 channel-last
__global__ __launch_bounds__(256) void tp_planes_kernel(const float* __restrict__ in,
                                                        __half* __restrict__ out) {
    unsigned idx = blockIdx.x * 256u + threadIdx.x;
    if (idx >= 3u * RES2) return;
    unsigned p  = idx / RES2;
    unsigned yx = idx - p * RES2;
    const float* src = in + (size_t)p * NC * RES2 + yx;
    unsigned short v[NC];
#pragma unroll
    for (int c = 0; c < NC; ++c) {
        __half h = __float2half(src[(size_t)c * RES2]);
        v[c] = *reinterpret_cast<unsigned short*>(&h);
    }
    // 48 halves = 96 B per texel; base is 16B-aligned (96 % 16 == 0)
    u32x4* dst = reinterpret_cast<u32x4*>(out + (size_t)idx * NC);
#pragma unroll
    for (int i = 0; i < 6; ++i) {
        u32x4 w;
        w.x = (unsigned)v[8 * i + 0] | ((unsigned)v[8 * i + 1] << 16);
        w.y = (unsigned)v[8 * i + 2] | ((unsigned)v[8 * i + 3] << 16);
        w.z = (unsigned)v[8 * i + 4] | ((unsigned)v[8 * i + 5] << 16);
        w.w = (unsigned)v[8 * i + 6] | ((unsigned)v[8 * i + 7] << 16);
        dst[i] = w;
    }
}

// (3, NC, RES, 1) fp32 -> (3, RES, NC) fp16 channel-last
__global__ __launch_bounds__(256) void tp_lines_kernel(const float* __restrict__ in,
                                                       __half* __restrict__ out) {
    unsigned idx = blockIdx.x * 256u + threadIdx.x;
    if (idx >= 3u * RES) return;
    unsigned p = idx / RES;
    unsigned y = idx - p * RES;
#pragma unroll
    for (int c = 0; c < NC; ++c)
        out[(size_t)idx * NC + c] = __float2half(in[((size_t)p * NC + c) * RES + y]);
}

// one thread per (point, 4-channel group): q in [0,36), p = q/12, c4 = q%12
__global__ __launch_bounds__(256) void encode_kernel(const float* __restrict__ x,
                                                     const __half* __restrict__ pt,  // (3,RES,RES,NC)
                                                     const __half* __restrict__ lt,  // (3,RES,NC)
                                                     float* __restrict__ out,
                                                     unsigned N) {
    unsigned gid = blockIdx.x * 256u + threadIdx.x;
    if (gid >= N * 36u) return;
    unsigned n  = gid / 36u;
    unsigned q  = gid - n * 36u;
    unsigned p  = q / 12u;
    unsigned c4 = q - p * 12u;

    float xv0 = x[3u * n + 0u];
    float xv1 = x[3u * n + 1u];
    float xv2 = x[3u * n + 2u];

    // p=0: gx=xs0 gy=xs1 gl=xs2 ; p=1: gx=xs0 gy=xs2 gl=xs1 ; p=2: gx=xs1 gy=xs2 gl=xs0
    float gxv = (p == 2u) ? xv1 : xv0;
    float gyv = (p == 0u) ? xv1 : xv2;
    float glv = (p == 0u) ? xv2 : ((p == 1u) ? xv1 : xv0);

    float gxs = 2.0f * gxv - 1.0f;
    float gys = 2.0f * gyv - 1.0f;
    float gls = 2.0f * glv - 1.0f;
    float px = (gxs + 1.0f) * 0.5f * (float)(RES - 1);
    float py = (gys + 1.0f) * 0.5f * (float)(RES - 1);
    float pl = (gls + 1.0f) * 0.5f * (float)(RES - 1);

    float x0f = floorf(px), y0f = floorf(py), l0f = floorf(pl);
    float wx = px - x0f, wy = py - y0f, wl = pl - l0f;

    int ix0 = clampi((int)x0f, 0, RES - 1);
    int ix1 = ix0 + 1 > RES - 1 ? RES - 1 : ix0 + 1;
    int iy0 = clampi((int)y0f, 0, RES - 1);
    int iy1 = iy0 + 1 > RES - 1 ? RES - 1 : iy0 + 1;
    int il0 = clampi((int)l0f, 0, RES - 1);
    int il1 = il0 + 1 > RES - 1 ? RES - 1 : il0 + 1;

    unsigned cbase = c4 * 4u;
    const __half* pb = pt + (size_t)p * RES2 * NC;
    unsigned o00 = ((unsigned)iy0 * RES + (unsigned)ix0) * NC + cbase;
    unsigned o01 = ((unsigned)iy0 * RES + (unsigned)ix1) * NC + cbase;
    unsigned o10 = ((unsigned)iy1 * RES + (unsigned)ix0) * NC + cbase;
    unsigned o11 = ((unsigned)iy1 * RES + (unsigned)ix1) * NC + cbase;

    h4 v00 = *reinterpret_cast<const h4*>(pb + o00);
    h4 v01 = *reinterpret_cast<const h4*>(pb + o01);
    h4 v10 = *reinterpret_cast<const h4*>(pb + o10);
    h4 v11 = *reinterpret_cast<const h4*>(pb + o11);

    float2 f00a = __half22float2(v00.a), f00b = __half22float2(v00.b);
    float2 f01a = __half22float2(v01.a), f01b = __half22float2(v01.b);
    float2 f10a = __half22float2(v10.a), f10b = __half22float2(v10.b);
    float2 f11a = __half22float2(v11.a), f11b = __half22float2(v11.b);

    float w00 = (1.0f - wx) * (1.0f - wy);
    float w01 = wx * (1.0f - wy);
    float w10 = (1.0f - wx) * wy;
    float w11 = wx * wy;

    f32x4 plane_v;
    plane_v.x = f00a.x * w00 + f01a.x * w01 + f10a.x * w10 + f11a.x * w11;
    plane_v.y = f00a.y * w00 + f01a.y * w01 + f10a.y * w10 + f11a.y * w11;
    plane_v.z = f00b.x * w00 + f01b.x * w01 + f10b.x * w10 + f11b.x * w11;
    plane_v.w = f00b.y * w00 + f01b.y * w01 + f10b.y * w10 + f11b.y * w11;

    const __half* lb = lt + (size_t)p * RES * NC + cbase;
    h4 vl0 = *reinterpret_cast<const h4*>(lb + (size_t)il0 * NC);
    h4 vl1 = *reinterpret_cast<const h4*>(lb + (size_t)il1 * NC);
    float2 l0a = __half22float2(vl0.a), l0b = __half22float2(vl0.b);
    float2 l1a = __half22float2(vl1.a), l1b = __half22float2(vl1.b);

    float wl0 = 1.0f - wl;
    f32x4 line_v;
    line_v.x = l0a.x * wl0 + l1a.x * wl;
    line_v.y = l0a.y * wl0 + l1a.y * wl;
    line_v.z = l0b.x * wl0 + l1b.x * wl;
    line_v.w = l0b.y * wl0 + l1b.y * wl;

    f32x4 r = plane_v * line_v;

    __builtin_nontemporal_store(r, reinterpret_cast<f32x4*>(out + (size_t)n * 144u + (size_t)q * 4u));
}

// correctness fallback if d_ws too small: gather from the original channel-major layout
__global__ __launch_bounds__(256) void encode_fallback_kernel(const float* __restrict__ x,
                                                              const float* __restrict__ plane,  // (3,NC,RES,RES)
                                                              const float* __restrict__ line,   // (3,NC,RES,1)
                                                              float* __restrict__ out,
                                                              unsigned N) {
    unsigned gid = blockIdx.x * 256u + threadIdx.x;
    if (gid >= N * 36u) return;
    unsigned n  = gid / 36u;
    unsigned q  = gid - n * 36u;
    unsigned p  = q / 12u;
    unsigned c4 = q - p * 12u;

    float xv0 = x[3u * n + 0u];
    float xv1 = x[3u * n + 1u];
    float xv2 = x[3u * n + 2u];
    float gxv = (p == 2u) ? xv1 : xv0;
    float gyv = (p == 0u) ? xv1 : xv2;
    float glv = (p == 0u) ? xv2 : ((p == 1u) ? xv1 : xv0);

    float gxs = 2.0f * gxv - 1.0f;
    float gys = 2.0f * gyv - 1.0f;
    float gls = 2.0f * glv - 1.0f;
    float px = (gxs + 1.0f) * 0.5f * (float)(RES - 1);
    float py = (gys + 1.0f) * 0.5f * (float)(RES - 1);
    float pl = (gls + 1.0f) * 0.5f * (float)(RES - 1);

    float x0f = floorf(px), y0f = floorf(py), l0f = floorf(pl);
    float wx = px - x0f, wy = py - y0f, wl = pl - l0f;

    int ix0 = clampi((int)x0f, 0, RES - 1);
    int ix1 = ix0 + 1 > RES - 1 ? RES - 1 : ix0 + 1;
    int iy0 = clampi((int)y0f, 0, RES - 1);
    int iy1 = iy0 + 1 > RES - 1 ? RES - 1 : iy0 + 1;
    int il0 = clampi((int)l0f, 0, RES - 1);
    int il1 = il0 + 1 > RES - 1 ? RES - 1 : il0 + 1;

    float w00 = (1.0f - wx) * (1.0f - wy);
    float w01 = wx * (1.0f - wy);
    float w10 = (1.0f - wx) * wy;
    float w11 = wx * wy;
    float wl0 = 1.0f - wl;

    float4 r;
    float* rp = &r.x;
#pragma unroll
    for (int cc = 0; cc < 4; ++cc) {
        unsigned c = c4 * 4u + (unsigned)cc;
        const float* pp = plane + ((size_t)p * NC + c) * RES2;
        float f00 = pp[(size_t)iy0 * RES + ix0];
        float f01 = pp[(size_t)iy0 * RES + ix1];
        float f10 = pp[(size_t)iy1 * RES + ix0];
        float f11 = pp[(size_t)iy1 * RES + ix1];
        float pv = f00 * w00 + f01 * w01 + f10 * w10 + f11 * w11;
        const float* lp = line + ((size_t)p * NC + c) * RES;
        float lv = lp[il0] * wl0 + lp[il1] * wl;
        rp[cc] = pv * lv;
    }
    *reinterpret_cast<float4*>(out + (size_t)n * 144u + (size_t)q * 4u) = r;
}

extern "C" void kernel_launch(void* const* d_in, const int* in_sizes, int n_in,
                              void* d_out, int out_size, void* d_ws, size_t ws_size,
                              hipStream_t stream) {
    const float* x     = (const float*)d_in[0];
    const float* plane = (const float*)d_in[1];
    const float* line  = (const float*)d_in[2];
    float* out = (float*)d_out;
    unsigned N = (unsigned)(in_sizes[0] / 3);

    size_t plane_t_elems = (size_t)3 * RES2 * NC;
    size_t line_t_elems  = (size_t)3 * RES * NC;
    size_t need = (plane_t_elems + line_t_elems) * sizeof(__half);

    unsigned total  = N * 36u;
    unsigned blocks = (total + 255u) / 256u;

    if (ws_size >= need) {
        __half* plane_t = (__half*)d_ws;
        __half* line_t  = plane_t + plane_t_elems;
        tp_planes_kernel<<<(3u * RES2 + 255u) / 256u, 256, 0, stream>>>(plane, plane_t);
        tp_lines_kernel<<<(3u * RES + 255u) / 256u, 256, 0, stream>>>(line, line_t);
        encode_kernel<<<blocks, 256, 0, stream>>>(x, plane_t, line_t, out, N);
    } else {
        encode_fallback_kernel<<<blocks, 256, 0, stream>>>(x, plane, line, out, N);
    }
}

// Round 3
// 293.544 us; speedup vs baseline: 1.6389x; 1.0694x over previous
//
#include <hip/hip_runtime.h>
#include <hip/hip_fp16.h>

#define RES 300
#define NC 48
#define RES2 (RES * RES)
#define NBINS 32768  // 32^3 Morton cells

typedef float f32x4 __attribute__((ext_vector_type(4)));
typedef unsigned int u32x4 __attribute__((ext_vector_type(4)));

struct alignas(8) h4 { __half2 a, b; };

__device__ __forceinline__ int clampi(int v, int lo, int hi) {
    return v < lo ? lo : (v > hi ? hi : v);
}

// spread 5 bits: bit i -> bit 3i
__device__ __forceinline__ unsigned spread5(unsigned v) {
    v &= 31u;
    v = (v | (v << 8)) & 0x100Fu;
    v = (v | (v << 4)) & 0x10C3u;
    v = (v | (v << 2)) & 0x1249u;
    return v;
}

__device__ __forceinline__ unsigned morton_key(float a, float b, float c) {
    int ca = clampi((int)(a * 32.0f), 0, 31);
    int cb = clampi((int)(b * 32.0f), 0, 31);
    int cc = clampi((int)(c * 32.0f), 0, 31);
    return spread5((unsigned)ca) | (spread5((unsigned)cb) << 1) | (spread5((unsigned)cc) << 2);
}

// ---------------- table transpose (fp32 channel-major -> fp16 channel-last) ----------------

__global__ __launch_bounds__(256) void tp_planes_kernel(const float* __restrict__ in,
                                                        __half* __restrict__ out) {
    unsigned idx = blockIdx.x * 256u + threadIdx.x;
    if (idx >= 3u * RES2) return;
    unsigned p  = idx / RES2;
    unsigned yx = idx - p * RES2;
    const float* src = in + (size_t)p * NC * RES2 + yx;
    unsigned short v[NC];
#pragma unroll
    for (int c = 0; c < NC; ++c) {
        __half h = __float2half(src[(size_t)c * RES2]);
        v[c] = *reinterpret_cast<unsigned short*>(&h);
    }
    u32x4* dst = reinterpret_cast<u32x4*>(out + (size_t)idx * NC);
#pragma unroll
    for (int i = 0; i < 6; ++i) {
        u32x4 w;
        w.x = (unsigned)v[8 * i + 0] | ((unsigned)v[8 * i + 1] << 16);
        w.y = (unsigned)v[8 * i + 2] | ((unsigned)v[8 * i + 3] << 16);
        w.z = (unsigned)v[8 * i + 4] | ((unsigned)v[8 * i + 5] << 16);
        w.w = (unsigned)v[8 * i + 6] | ((unsigned)v[8 * i + 7] << 16);
        dst[i] = w;
    }
}

__global__ __launch_bounds__(256) void tp_lines_kernel(const float* __restrict__ in,
                                                       __half* __restrict__ out) {
    unsigned idx = blockIdx.x * 256u + threadIdx.x;
    if (idx >= 3u * RES) return;
    unsigned p = idx / RES;
    unsigned y = idx - p * RES;
#pragma unroll
    for (int c = 0; c < NC; ++c)
        out[(size_t)idx * NC + c] = __float2half(in[((size_t)p * NC + c) * RES + y]);
}

// ---------------- Morton counting sort ----------------

__global__ __launch_bounds__(256) void zero_bins_kernel(unsigned* __restrict__ counts) {
    unsigned i = blockIdx.x * 256u + threadIdx.x;
    if (i < NBINS) counts[i] = 0u;
}

__global__ __launch_bounds__(256) void hist_kernel(const float* __restrict__ x,
                                                   unsigned* __restrict__ counts,
                                                   unsigned N) {
    unsigned i = blockIdx.x * 256u + threadIdx.x;
    if (i >= N) return;
    unsigned k = morton_key(x[3u * i], x[3u * i + 1u], x[3u * i + 2u]);
    atomicAdd(&counts[k], 1u);
}

// one block, 1024 threads; exclusive scan of NBINS counts -> offs
__global__ __launch_bounds__(1024) void scan_kernel(const unsigned* __restrict__ counts,
                                                    unsigned* __restrict__ offs) {
    __shared__ unsigned part[1024];
    int t = threadIdx.x;
    unsigned local[NBINS / 1024];
    unsigned s = 0;
#pragma unroll
    for (int j = 0; j < NBINS / 1024; ++j) {
        local[j] = counts[t * (NBINS / 1024) + j];
        s += local[j];
    }
    part[t] = s;
    __syncthreads();
    for (int d = 1; d < 1024; d <<= 1) {
        unsigned v = (t >= d) ? part[t - d] : 0u;
        __syncthreads();
        part[t] += v;
        __syncthreads();
    }
    unsigned run = (t == 0) ? 0u : part[t - 1];
#pragma unroll
    for (int j = 0; j < NBINS / 1024; ++j) {
        offs[t * (NBINS / 1024) + j] = run;
        run += local[j];
    }
}

// scatter points into Morton order; offs is consumed (becomes end offsets)
__global__ __launch_bounds__(256) void scatter_kernel(const float* __restrict__ x,
                                                      unsigned* __restrict__ offs,
                                                      f32x4* __restrict__ sorted,
                                                      unsigned N) {
    unsigned i = blockIdx.x * 256u + threadIdx.x;
    if (i >= N) return;
    float a = x[3u * i], b = x[3u * i + 1u], c = x[3u * i + 2u];
    unsigned k = morton_key(a, b, c);
    unsigned pos = atomicAdd(&offs[k], 1u);
    f32x4 v;
    v.x = a; v.y = b; v.z = c; v.w = __uint_as_float(i);
    sorted[pos] = v;
}

// ---------------- encode (sorted, XCD-chunked swizzle) ----------------

__global__ __launch_bounds__(256) void encode_sorted_kernel(const f32x4* __restrict__ sorted,
                                                            const __half* __restrict__ pt,  // (3,RES,RES,NC)
                                                            const __half* __restrict__ lt,  // (3,RES,NC)
                                                            float* __restrict__ out,
                                                            unsigned N) {
    // bijective XCD chunking (m204 variant): each XCD gets a contiguous chunk of
    // the Morton-sorted point range -> per-XCD L2 working set ~1/8 of the table.
    unsigned nwg  = gridDim.x;
    unsigned orig = blockIdx.x;
    unsigned xcd = orig & 7u, j = orig >> 3u;
    unsigned qq = nwg >> 3u, r = nwg & 7u;
    unsigned bid = (xcd < r ? xcd * (qq + 1u) : r * (qq + 1u) + (xcd - r) * qq) + j;

    unsigned gid = bid * 256u + threadIdx.x;
    if (gid >= N * 36u) return;
    unsigned s  = gid / 36u;
    unsigned q  = gid - s * 36u;
    unsigned p  = q / 12u;
    unsigned c4 = q - p * 12u;

    f32x4 pv4 = sorted[s];
    float xv0 = pv4.x, xv1 = pv4.y, xv2 = pv4.z;
    unsigned n = __float_as_uint(pv4.w);

    // p=0: gx=xs0 gy=xs1 gl=xs2 ; p=1: gx=xs0 gy=xs2 gl=xs1 ; p=2: gx=xs1 gy=xs2 gl=xs0
    float gxv = (p == 2u) ? xv1 : xv0;
    float gyv = (p == 0u) ? xv1 : xv2;
    float glv = (p == 0u) ? xv2 : ((p == 1u) ? xv1 : xv0);

    float gxs = 2.0f * gxv - 1.0f;
    float gys = 2.0f * gyv - 1.0f;
    float gls = 2.0f * glv - 1.0f;
    float px = (gxs + 1.0f) * 0.5f * (float)(RES - 1);
    float py = (gys + 1.0f) * 0.5f * (float)(RES - 1);
    float pl = (gls + 1.0f) * 0.5f * (float)(RES - 1);

    float x0f = floorf(px), y0f = floorf(py), l0f = floorf(pl);
    float wx = px - x0f, wy = py - y0f, wl = pl - l0f;

    int ix0 = clampi((int)x0f, 0, RES - 1);
    int ix1 = ix0 + 1 > RES - 1 ? RES - 1 : ix0 + 1;
    int iy0 = clampi((int)y0f, 0, RES - 1);
    int iy1 = iy0 + 1 > RES - 1 ? RES - 1 : iy0 + 1;
    int il0 = clampi((int)l0f, 0, RES - 1);
    int il1 = il0 + 1 > RES - 1 ? RES - 1 : il0 + 1;

    unsigned cbase = c4 * 4u;
    const __half* pb = pt + (size_t)p * RES2 * NC;
    unsigned o00 = ((unsigned)iy0 * RES + (unsigned)ix0) * NC + cbase;
    unsigned o01 = ((unsigned)iy0 * RES + (unsigned)ix1) * NC + cbase;
    unsigned o10 = ((unsigned)iy1 * RES + (unsigned)ix0) * NC + cbase;
    unsigned o11 = ((unsigned)iy1 * RES + (unsigned)ix1) * NC + cbase;

    h4 v00 = *reinterpret_cast<const h4*>(pb + o00);
    h4 v01 = *reinterpret_cast<const h4*>(pb + o01);
    h4 v10 = *reinterpret_cast<const h4*>(pb + o10);
    h4 v11 = *reinterpret_cast<const h4*>(pb + o11);

    float2 f00a = __half22float2(v00.a), f00b = __half22float2(v00.b);
    float2 f01a = __half22float2(v01.a), f01b = __half22float2(v01.b);
    float2 f10a = __half22float2(v10.a), f10b = __half22float2(v10.b);
    float2 f11a = __half22float2(v11.a), f11b = __half22float2(v11.b);

    float w00 = (1.0f - wx) * (1.0f - wy);
    float w01 = wx * (1.0f - wy);
    float w10 = (1.0f - wx) * wy;
    float w11 = wx * wy;

    f32x4 plane_v;
    plane_v.x = f00a.x * w00 + f01a.x * w01 + f10a.x * w10 + f11a.x * w11;
    plane_v.y = f00a.y * w00 + f01a.y * w01 + f10a.y * w10 + f11a.y * w11;
    plane_v.z = f00b.x * w00 + f01b.x * w01 + f10b.x * w10 + f11b.x * w11;
    plane_v.w = f00b.y * w00 + f01b.y * w01 + f10b.y * w10 + f11b.y * w11;

    const __half* lb = lt + (size_t)p * RES * NC + cbase;
    h4 vl0 = *reinterpret_cast<const h4*>(lb + (size_t)il0 * NC);
    h4 vl1 = *reinterpret_cast<const h4*>(lb + (size_t)il1 * NC);
    float2 l0a = __half22float2(vl0.a), l0b = __half22float2(vl0.b);
    float2 l1a = __half22float2(vl1.a), l1b = __half22float2(vl1.b);

    float wl0 = 1.0f - wl;
    f32x4 line_v;
    line_v.x = l0a.x * wl0 + l1a.x * wl;
    line_v.y = l0a.y * wl0 + l1a.y * wl;
    line_v.z = l0b.x * wl0 + l1b.x * wl;
    line_v.w = l0b.y * wl0 + l1b.y * wl;

    f32x4 rr = plane_v * line_v;

    __builtin_nontemporal_store(rr, reinterpret_cast<f32x4*>(out + (size_t)n * 144u + (size_t)q * 4u));
}

// ---------------- unsorted encode (fallback when ws fits only tables) ----------------

__global__ __launch_bounds__(256) void encode_kernel(const float* __restrict__ x,
                                                     const __half* __restrict__ pt,
                                                     const __half* __restrict__ lt,
                                                     float* __restrict__ out,
                                                     unsigned N) {
    unsigned gid = blockIdx.x * 256u + threadIdx.x;
    if (gid >= N * 36u) return;
    unsigned n  = gid / 36u;
    unsigned q  = gid - n * 36u;
    unsigned p  = q / 12u;
    unsigned c4 = q - p * 12u;

    float xv0 = x[3u * n + 0u];
    float xv1 = x[3u * n + 1u];
    float xv2 = x[3u * n + 2u];
    float gxv = (p == 2u) ? xv1 : xv0;
    float gyv = (p == 0u) ? xv1 : xv2;
    float glv = (p == 0u) ? xv2 : ((p == 1u) ? xv1 : xv0);

    float gxs = 2.0f * gxv - 1.0f;
    float gys = 2.0f * gyv - 1.0f;
    float gls = 2.0f * glv - 1.0f;
    float px = (gxs + 1.0f) * 0.5f * (float)(RES - 1);
    float py = (gys + 1.0f) * 0.5f * (float)(RES - 1);
    float pl = (gls + 1.0f) * 0.5f * (float)(RES - 1);

    float x0f = floorf(px), y0f = floorf(py), l0f = floorf(pl);
    float wx = px - x0f, wy = py - y0f, wl = pl - l0f;

    int ix0 = clampi((int)x0f, 0, RES - 1);
    int ix1 = ix0 + 1 > RES - 1 ? RES - 1 : ix0 + 1;
    int iy0 = clampi((int)y0f, 0, RES - 1);
    int iy1 = iy0 + 1 > RES - 1 ? RES - 1 : iy0 + 1;
    int il0 = clampi((int)l0f, 0, RES - 1);
    int il1 = il0 + 1 > RES - 1 ? RES - 1 : il0 + 1;

    unsigned cbase = c4 * 4u;
    const __half* pb = pt + (size_t)p * RES2 * NC;
    h4 v00 = *reinterpret_cast<const h4*>(pb + ((unsigned)iy0 * RES + (unsigned)ix0) * NC + cbase);
    h4 v01 = *reinterpret_cast<const h4*>(pb + ((unsigned)iy0 * RES + (unsigned)ix1) * NC + cbase);
    h4 v10 = *reinterpret_cast<const h4*>(pb + ((unsigned)iy1 * RES + (unsigned)ix0) * NC + cbase);
    h4 v11 = *reinterpret_cast<const h4*>(pb + ((unsigned)iy1 * RES + (unsigned)ix1) * NC + cbase);

    float2 f00a = __half22float2(v00.a), f00b = __half22float2(v00.b);
    float2 f01a = __half22float2(v01.a), f01b = __half22float2(v01.b);
    float2 f10a = __half22float2(v10.a), f10b = __half22float2(v10.b);
    float2 f11a = __half22float2(v11.a), f11b = __half22float2(v11.b);

    float w00 = (1.0f - wx) * (1.0f - wy);
    float w01 = wx * (1.0f - wy);
    float w10 = (1.0f - wx) * wy;
    float w11 = wx * wy;

    f32x4 plane_v;
    plane_v.x = f00a.x * w00 + f01a.x * w01 + f10a.x * w10 + f11a.x * w11;
    plane_v.y = f00a.y * w00 + f01a.y * w01 + f10a.y * w10 + f11a.y * w11;
    plane_v.z = f00b.x * w00 + f01b.x * w01 + f10b.x * w10 + f11b.x * w11;
    plane_v.w = f00b.y * w00 + f01b.y * w01 + f10b.y * w10 + f11b.y * w11;

    const __half* lb = lt + (size_t)p * RES * NC + cbase;
    h4 vl0 = *reinterpret_cast<const h4*>(lb + (size_t)il0 * NC);
    h4 vl1 = *reinterpret_cast<const h4*>(lb + (size_t)il1 * NC);
    float2 l0a = __half22float2(vl0.a), l0b = __half22float2(vl0.b);
    float2 l1a = __half22float2(vl1.a), l1b = __half22float2(vl1.b);

    float wl0 = 1.0f - wl;
    f32x4 line_v;
    line_v.x = l0a.x * wl0 + l1a.x * wl;
    line_v.y = l0a.y * wl0 + l1a.y * wl;
    line_v.z = l0b.x * wl0 + l1b.x * wl;
    line_v.w = l0b.y * wl0 + l1b.y * wl;

    f32x4 rr = plane_v * line_v;
    __builtin_nontemporal_store(rr, reinterpret_cast<f32x4*>(out + (size_t)n * 144u + (size_t)q * 4u));
}

// last-resort fallback: gather from original channel-major layout
__global__ __launch_bounds__(256) void encode_fallback_kernel(const float* __restrict__ x,
                                                              const float* __restrict__ plane,
                                                              const float* __restrict__ line,
                                                              float* __restrict__ out,
                                                              unsigned N) {
    unsigned gid = blockIdx.x * 256u + threadIdx.x;
    if (gid >= N * 36u) return;
    unsigned n  = gid / 36u;
    unsigned q  = gid - n * 36u;
    unsigned p  = q / 12u;
    unsigned c4 = q - p * 12u;

    float xv0 = x[3u * n + 0u];
    float xv1 = x[3u * n + 1u];
    float xv2 = x[3u * n + 2u];
    float gxv = (p == 2u) ? xv1 : xv0;
    float gyv = (p == 0u) ? xv1 : xv2;
    float glv = (p == 0u) ? xv2 : ((p == 1u) ? xv1 : xv0);

    float gxs = 2.0f * gxv - 1.0f;
    float gys = 2.0f * gyv - 1.0f;
    float gls = 2.0f * glv - 1.0f;
    float px = (gxs + 1.0f) * 0.5f * (float)(RES - 1);
    float py = (gys + 1.0f) * 0.5f * (float)(RES - 1);
    float pl = (gls + 1.0f) * 0.5f * (float)(RES - 1);

    float x0f = floorf(px), y0f = floorf(py), l0f = floorf(pl);
    float wx = px - x0f, wy = py - y0f, wl = pl - l0f;

    int ix0 = clampi((int)x0f, 0, RES - 1);
    int ix1 = ix0 + 1 > RES - 1 ? RES - 1 : ix0 + 1;
    int iy0 = clampi((int)y0f, 0, RES - 1);
    int iy1 = iy0 + 1 > RES - 1 ? RES - 1 : iy0 + 1;
    int il0 = clampi((int)l0f, 0, RES - 1);
    int il1 = il0 + 1 > RES - 1 ? RES - 1 : il0 + 1;

    float w00 = (1.0f - wx) * (1.0f - wy);
    float w01 = wx * (1.0f - wy);
    float w10 = (1.0f - wx) * wy;
    float w11 = wx * wy;
    float wl0 = 1.0f - wl;

    float4 r;
    float* rp = &r.x;
#pragma unroll
    for (int cc = 0; cc < 4; ++cc) {
        unsigned c = c4 * 4u + (unsigned)cc;
        const float* pp = plane + ((size_t)p * NC + c) * RES2;
        float f00 = pp[(size_t)iy0 * RES + ix0];
        float f01 = pp[(size_t)iy0 * RES + ix1];
        float f10 = pp[(size_t)iy1 * RES + ix0];
        float f11 = pp[(size_t)iy1 * RES + ix1];
        float pv = f00 * w00 + f01 * w01 + f10 * w10 + f11 * w11;
        const float* lp = line + ((size_t)p * NC + c) * RES;
        float lv = lp[il0] * wl0 + lp[il1] * wl;
        rp[cc] = pv * lv;
    }
    *reinterpret_cast<float4*>(out + (size_t)n * 144u + (size_t)q * 4u) = r;
}

extern "C" void kernel_launch(void* const* d_in, const int* in_sizes, int n_in,
                              void* d_out, int out_size, void* d_ws, size_t ws_size,
                              hipStream_t stream) {
    const float* x     = (const float*)d_in[0];
    const float* plane = (const float*)d_in[1];
    const float* line  = (const float*)d_in[2];
    float* out = (float*)d_out;
    unsigned N = (unsigned)(in_sizes[0] / 3);

    size_t plane_t_elems = (size_t)3 * RES2 * NC;
    size_t line_t_elems  = (size_t)3 * RES * NC;
    size_t sorted_bytes  = (size_t)N * 16u;
    size_t plane_bytes   = plane_t_elems * sizeof(__half);
    size_t line_bytes    = line_t_elems * sizeof(__half);
    size_t bins_bytes    = (size_t)NBINS * 4u;

    size_t need_mid  = plane_bytes + line_bytes;
    size_t need_full = sorted_bytes + plane_bytes + line_bytes + 2u * bins_bytes;

    unsigned total  = N * 36u;
    unsigned blocks = (total + 255u) / 256u;
    unsigned pblocks = (N + 255u) / 256u;

    if (ws_size >= need_full) {
        char* base = (char*)d_ws;
        f32x4*   sorted  = (f32x4*)base;                      base += sorted_bytes;
        __half*  plane_t = (__half*)base;                     base += plane_bytes;
        __half*  line_t  = (__half*)base;                     base += line_bytes;
        unsigned* counts = (unsigned*)base;                   base += bins_bytes;
        unsigned* offs   = (unsigned*)base;

        zero_bins_kernel<<<(NBINS + 255) / 256, 256, 0, stream>>>(counts);
        hist_kernel<<<pblocks, 256, 0, stream>>>(x, counts, N);
        tp_planes_kernel<<<(3u * RES2 + 255u) / 256u, 256, 0, stream>>>(plane, plane_t);
        tp_lines_kernel<<<(3u * RES + 255u) / 256u, 256, 0, stream>>>(line, line_t);
        scan_kernel<<<1, 1024, 0, stream>>>(counts, offs);
        scatter_kernel<<<pblocks, 256, 0, stream>>>(x, offs, sorted, N);
        encode_sorted_kernel<<<blocks, 256, 0, stream>>>(sorted, plane_t, line_t, out, N);
    } else if (ws_size >= need_mid) {
        __half* plane_t = (__half*)d_ws;
        __half* line_t  = plane_t + plane_t_elems;
        tp_planes_kernel<<<(3u * RES2 + 255u) / 256u, 256, 0, stream>>>(plane, plane_t);
        tp_lines_kernel<<<(3u * RES + 255u) / 256u, 256, 0, stream>>>(line, line_t);
        encode_kernel<<<blocks, 256, 0, stream>>>(x, plane_t, line_t, out, N);
    } else {
        encode_fallback_kernel<<<blocks, 256, 0, stream>>>(x, plane, line, out, N);
    }
}